// Round 5
// baseline (253.965 us; speedup 1.0000x reference)
//
#include <hip/hip_runtime.h>

#define PI_F 3.14159265358979323846f

// ws layout (bytes):
//   0        : trig table — f32 cosphi[1024], sinphi[1024], costh[512],
//              sinth[512] = 12288 B (written by trig_kernel, read by bin)
//   24576    : maxz — u32 maxraw[3*32] then maxdiff[3] (zeroed by trig blk 0)
//   32768    : packed hist u8: 3 planes × 32 hists × 262144 bins = 24 MB
//   25198592 : bucket regions: 4096 bin-blocks × 24672 B each
//              (96 B header: u16 cumoff[1..48] (off[0]==0 implicit);
//               24576 B data: 12288 u16 in-band ids segmented by
//               bucket = plane*16 + band32)  -> ws end ≈ 126.26 MB
#define MAXZ_OFF_B   24576
#define HIST_OFF_B   32768
#define BUCK_OFF_B   25198592
#define REGION_U16   12336          // region stride in u16 units (24672 B)

// Correctly-rounded a/20000 via Markstein refinement (bit-exact RN).
__device__ inline float div20000(float a) {
    const float r = 1.0f / 20000.0f;
    float q0 = a * r;
    float e = fmaf(-20000.0f, q0, a);
    return fmaf(e, r, q0);
}

__device__ inline int bin1(float v) {
    float f = rintf(div20000(v + 10000.0f) * 512.0f);
    return (int)fminf(fmaxf(f, 0.0f), 511.0f);
}

// Pass 0: compute the 1024 phi + 512 theta sin/cos pairs ONCE. Identical FP
// expressions to the original -> bit-identical values. Block 0 also zeroes
// maxz + out (kernel boundary orders this before scan/loss).
__global__ __launch_bounds__(256) void trig_kernel(
    float* __restrict__ tbl, unsigned* __restrict__ maxz,
    float* __restrict__ out) {
    const int t = threadIdx.x + blockIdx.x * 256;
    if (blockIdx.x == 0) {
        if (threadIdx.x < 128) maxz[threadIdx.x] = 0u;
        if (threadIdx.x == 128) out[0] = 0.0f;
    }
    if (t < 1024) {
        float fj = (float)t;
        float phi = PI_F * ((2.0f * fj) / 1023.0f - 1.0f);
        tbl[t] = cosf(phi);
        tbl[1024 + t] = sinf(phi);
    } else {
        int i = t - 1024;                       // < 512
        float fi = (float)i;
        float theta = -PI_F * (fi / 511.0f - 0.5f);
        tbl[2048 + i] = cosf(theta);
        tbl[2560 + i] = sinf(theta);
    }
}

// Pass 1: 4096 blocks = (xcd[0:2], i4[3:9], hh[10:11]), 4 rows/block,
// XCD-pinned (wg&7 == h&7). Bucket-sort of 4096 points × 3 planes into 48
// (plane, 32-row band) segments.
//  * 48 buckets (finer bands) so scan can run 1536 smaller blocks — the
//    center-band load imbalance was scan's makespan limiter.
//  * cnt stride padded to 33: atomic phase stays ~2-way; the 48-thread
//    prefix loop spreads (b+r)%32 over all banks.
// Worst-case per (bucket,rep): 8 threads × 16 same-plane items = 128 ->
// rank 0..127 fits 7 bits: item = [bucket:6][rep:5][rank:7][id:14].
// Ranks nondeterministic, counts exact -> downstream bit-identical.
__global__ __launch_bounds__(256) void bin_kernel(
    const float* __restrict__ pred, const float* __restrict__ gt,
    const float* __restrict__ tbl, unsigned short* __restrict__ buck) {
    __shared__ unsigned cnt[1584];              // 48 buckets × stride 33
    __shared__ unsigned bsum[48];
    __shared__ unsigned off[49];
    __shared__ __align__(16) unsigned short sdata[12288];
    const int tid = threadIdx.x, wg = blockIdx.x;
    const unsigned rep = (unsigned)(tid & 31);
    const int xcd = wg & 7, i4 = (wg >> 3) & 127, hh = wg >> 10;
    const int h = (hh << 3) | xcd;
    #pragma unroll
    for (int z = 0; z < 7; ++z) {
        int idx = tid + (z << 8);
        if (idx < 1584) cnt[idx] = 0u;
    }
    const float4 cp4 = *(const float4*)&tbl[tid << 2];          // cos phi
    const float4 sp4 = *(const float4*)&tbl[1024 + (tid << 2)]; // sin phi
    const float4 ct4 = *(const float4*)&tbl[2048 + (i4 << 2)];  // cos theta
    const float4 st4 = *(const float4*)&tbl[2560 + (i4 << 2)];  // sin theta
    __syncthreads();
    const float* img = ((h >> 4) ? gt : pred) + ((h & 15) << 19);
    // item = [bucket:6][rep:5][rank:7][id:14]
    unsigned items[48];
    #pragma unroll
    for (int r = 0; r < 4; ++r) {
        const int i = i4 * 4 + r;
        const float4 d4 = *(const float4*)(img + (i << 10) + (tid << 2));
        const float ct = (&ct4.x)[r], st = (&st4.x)[r];
        #pragma unroll
        for (int k = 0; k < 4; ++k) {
            float d = (&d4.x)[k];
            float aA = (&cp4.x)[k] * ct;        // identical op order to r3/r5
            float aB = (&sp4.x)[k] * ct;
            float A = (d * aA) * 1000.0f;
            float B = (d * aB) * 1000.0f;
            float C = (d * (-st)) * 1000.0f;
            int iA = bin1(A), iB = bin1(B), iC = bin1(C);
            // plane0: y=iB,x=iA; plane1: y=iC,x=iA; plane2: y=iC,x=iB
            unsigned f0 = ((unsigned)iB << 9) | (unsigned)iA;   // 18-bit y*512+x
            unsigned f1 = ((unsigned)iC << 9) | (unsigned)iA;
            unsigned f2 = ((unsigned)iC << 9) | (unsigned)iB;
            unsigned b0 = f0 >> 14;                             // band32 of y
            unsigned b1 = 16u + (f1 >> 14);
            unsigned b2 = 32u + (f2 >> 14);
            unsigned r0 = atomicAdd(&cnt[b0 * 33u + rep], 1u);
            unsigned r1 = atomicAdd(&cnt[b1 * 33u + rep], 1u);
            unsigned r2 = atomicAdd(&cnt[b2 * 33u + rep], 1u);
            const int base = (r * 4 + k) * 3;
            items[base + 0] = (b0 << 26) | (rep << 21) | (r0 << 14) | (f0 & 16383u);
            items[base + 1] = (b1 << 26) | (rep << 21) | (r1 << 14) | (f1 & 16383u);
            items[base + 2] = (b2 << 26) | (rep << 21) | (r2 << 14) | (f2 & 16383u);
        }
    }
    __syncthreads();
    // 3-level prefix: intra-bucket over 32 replicas (48 threads, stride-33
    // layout -> banks (b+r)%32, ~2-way), across 48 buckets (thread 0), then
    // convert cnt[] to absolute sub-segment bases.
    if (tid < 48) {
        unsigned s = 0;
        #pragma unroll
        for (int r = 0; r < 32; ++r) {
            unsigned t = cnt[tid * 33 + r];
            cnt[tid * 33 + r] = s;
            s += t;
        }
        bsum[tid] = s;
    }
    __syncthreads();
    if (tid == 0) {
        unsigned s = 0;
        #pragma unroll
        for (int b = 0; b < 48; ++b) { off[b] = s; s += bsum[b]; }
        off[48] = s;                            // == 12288
    }
    __syncthreads();
    if (tid < 48) {
        unsigned o = off[tid];
        #pragma unroll
        for (int r = 0; r < 32; ++r) cnt[tid * 33 + r] += o;
    }
    __syncthreads();
    // scatter into LDS staging (u16 scatter in LDS, ~2-way conflicts = free)
    #pragma unroll
    for (int t = 0; t < 48; ++t) {
        const unsigned it = items[t];
        const unsigned slot = (it >> 26) * 33u + ((it >> 21) & 31u);
        sdata[cnt[slot] + ((it >> 14) & 127u)] = (unsigned short)(it & 16383u);
    }
    __syncthreads();
    unsigned short* regG = buck + (size_t)wg * REGION_U16;
    // header: cumulative offsets off[1..48] (off[0]==0 implicit), 96 B
    if (tid < 48) regG[tid] = (unsigned short)off[tid + 1];
    // coalesced copy-out: 12288 u16 = 1536 uint4 = 6 per thread exactly
    const uint4* s4p = (const uint4*)sdata;
    uint4* g4 = (uint4*)(regG + 48);            // data after 96 B header
    #pragma unroll
    for (int c = 0; c < 6; ++c) g4[(c << 8) + tid] = s4p[(c << 8) + tid];
}

// Pass 2: 1536 blocks = (xcd[0:2]==h&7 (L2 pin), h>>3[3:4], X[5:10]);
// X=0..47 -> plane = X%3, band = LPT permutation (center bands first).
// 512 threads, 32 KB LDS hist (32 rows × 512 bins u16-packed), 4 blocks/CU.
// Each of 8 waves streams the block's bucket segments of 16 consecutive-i4
// regions: contiguous u16 ids read as uint4 with lane-local run-length merge
// (hot center segments are runs; merging collapses same-word atomic
// serialization). Region headers are software-pipelined.
// ROUND-4 BUGFIX: region linear index is xcd|(i4<<3)|(hh<<10) — i4 lives at
// bit 3, so stepping i4+1 is reg + 8*REGION_U16 (the +1*REGION_U16 step
// walked the xcd bits -> wrong regions, absmax 4e-3).
__global__ __launch_bounds__(512, 8) void scan_kernel(
    const unsigned short* __restrict__ buck, unsigned* __restrict__ hp,
    unsigned* __restrict__ maxraw) {
    __shared__ unsigned lh[8192];               // 32 rows × 512 bins, u16×2
    __shared__ unsigned s4[8];
    const int tid = threadIdx.x, wg = blockIdx.x;
    const int xcd = wg & 7, hhi = (wg >> 3) & 3;
    const int X = wg >> 5;                      // 0..47
    const int plane = X % 3;
    // band order (heavy center first): 7,8,6,9,5,10,4,11,3,12,2,13,1,14,0,15
    const unsigned long long PACKED = 0xF0E1D2C3B4A59687ULL;
    const int band = (int)((PACKED >> ((X / 3) * 4)) & 15);
    const int h = (hhi << 3) | xcd;
    const int bucket = plane * 16 + band;

    #pragma unroll
    for (int k = 0; k < 4; ++k)
        *(uint4*)&lh[(k << 11) + (tid << 2)] = make_uint4(0, 0, 0, 0);
    __syncthreads();

    const int wid = tid >> 6, lane = tid & 63;
    const unsigned short* reg =
        buck + (size_t)(xcd | ((wid << 4) << 3) | (hhi << 10)) * REGION_U16;
    int lo = bucket ? reg[bucket - 1] : 0;
    int hi = reg[bucket];
    for (int jj = 0; jj < 16; ++jj) {
        const unsigned short* data = reg + 48;
        // prefetch next region's header while processing this one
        const unsigned short* nreg = reg + 8 * (size_t)REGION_U16;  // i4+1
        int nlo = 0, nhi = 0;
        if (jj < 15) {
            nlo = bucket ? nreg[bucket - 1] : 0;
            nhi = nreg[bucket];
        }
        int a = (lo + 7) & ~7;                  // first 16B-aligned index
        if (a > hi) a = hi;
        const int head = a - lo;                // <= 7
        if (lane < head) {
            const unsigned id = data[lo + lane];
            atomicAdd(&lh[id >> 1], 1u << ((id & 1u) << 4));
        }
        const int nv = (hi - a) >> 3;           // full uint4 groups
        for (int v = lane; v < nv; v += 64) {
            const uint4 w = *(const uint4*)&data[a + (v << 3)];
            unsigned prev = w.x & 65535u, c = 1;
            auto step = [&](unsigned id) {
                if (id == prev) { ++c; }
                else {
                    atomicAdd(&lh[prev >> 1], c << ((prev & 1u) << 4));
                    prev = id; c = 1;
                }
            };
            step(w.x >> 16);
            step(w.y & 65535u); step(w.y >> 16);
            step(w.z & 65535u); step(w.z >> 16);
            step(w.w & 65535u); step(w.w >> 16);
            atomicAdd(&lh[prev >> 1], c << ((prev & 1u) << 4));
        }
        const int tail = (hi - a) & 7;          // <= 7
        if (lane < tail) {
            const unsigned id = data[a + (nv << 3) + lane];
            atomicAdd(&lh[id >> 1], 1u << ((id & 1u) << 4));
        }
        reg = nreg; lo = nlo; hi = nhi;
    }
    __syncthreads();

    // pack to u8 (sat 255; downstream clamps at 100) + raw band max
    unsigned m = 0;
    unsigned* gout = hp + ((plane * 32 + h) << 16) + (band << 12);
    #pragma unroll
    for (int k = 0; k < 8; ++k) {
        int w = (k << 9) + tid;
        unsigned v0 = lh[2 * w], v1 = lh[2 * w + 1];
        unsigned c0 = v0 & 65535u, c1 = v0 >> 16;
        unsigned c2 = v1 & 65535u, c3 = v1 >> 16;
        m = max(max(m, max(c0, c1)), max(c2, c3));
        gout[w] = min(c0, 255u) | (min(c1, 255u) << 8) |
                  (min(c2, 255u) << 16) | (min(c3, 255u) << 24);
    }
    #pragma unroll
    for (int o = 32; o; o >>= 1) m = max(m, (unsigned)__shfl_down((int)m, o));
    if ((tid & 63) == 0) s4[tid >> 6] = m;
    __syncthreads();
    if (tid == 0) {
        #pragma unroll
        for (int k = 1; k < 8; ++k) m = max(m, s4[k]);
        atomicMax(&maxraw[plane * 32 + h], m);
    }
}

__device__ inline float blockMaxF(float v) {
    #pragma unroll
    for (int o = 32; o; o >>= 1) v = fmaxf(v, __shfl_down(v, o));
    __shared__ float s[4];
    if ((threadIdx.x & 63) == 0) s[threadIdx.x >> 6] = v;
    __syncthreads();
    if (threadIdx.x == 0) v = fmaxf(fmaxf(s[0], s[1]), fmaxf(s[2], s[3]));
    return v;
}

__device__ inline float blockSumF(float v) {
    #pragma unroll
    for (int o = 32; o; o >>= 1) v += __shfl_down(v, o);
    __shared__ float s[4];
    if ((threadIdx.x & 63) == 0) s[threadIdx.x >> 6] = v;
    __syncthreads();
    if (threadIdx.x == 0) v = (s[0] + s[1]) + (s[2] + s[3]);
    return v;
}

// 768 blocks = 3 planes × 16 b × 16 chunks; uint4 loads, 16 bins/word-quad.
__global__ void maxdiff_kernel(const unsigned* __restrict__ hp,
                               const unsigned* __restrict__ maxraw,
                               unsigned* __restrict__ maxdiff) {
    int blk = blockIdx.x;
    int b = blk & 15, chunk = (blk >> 4) & 15, plane = blk >> 8;
    const unsigned* P = hp + ((plane * 32 + b) << 16) + (chunk << 12);
    const unsigned* G = P + (16 << 16);
    float nP = fminf((float)maxraw[plane * 32 + b], 100.0f);
    float nG = fminf((float)maxraw[plane * 32 + 16 + b], 100.0f);
    float m = 0.0f;
    #pragma unroll
    for (int k = 0; k < 4; ++k) {
        uint4 wp = *(const uint4*)&P[(k << 10) + (threadIdx.x << 2)];
        uint4 wg = *(const uint4*)&G[(k << 10) + (threadIdx.x << 2)];
        #pragma unroll
        for (int w = 0; w < 4; ++w) {
            unsigned up = (&wp.x)[w], ug = (&wg.x)[w];
            #pragma unroll
            for (int s = 0; s < 32; s += 8) {
                float pn = fminf((float)((up >> s) & 255u), 100.0f) / nP;
                float gn = fminf((float)((ug >> s) & 255u), 100.0f) / nG;
                m = fmaxf(m, fabsf(pn - gn));
            }
        }
    }
    m = blockMaxF(m);
    if (threadIdx.x == 0) atomicMax(&maxdiff[plane], __float_as_uint(m));
}

// Accumulates directly into out[0] (pre-zeroed by trig block 0):
// blocksum/2^22 is an exact power-of-2 scale, then one atomicAdd per block.
__global__ void loss_kernel(const unsigned* __restrict__ hp,
                            const unsigned* __restrict__ maxraw,
                            const unsigned* __restrict__ maxdiff,
                            float* __restrict__ out) {
    int blk = blockIdx.x;
    int b = blk & 15, chunk = (blk >> 4) & 15, plane = blk >> 8;
    const unsigned* P = hp + ((plane * 32 + b) << 16) + (chunk << 12);
    const unsigned* G = P + (16 << 16);
    float c = 0.2f * __uint_as_float(maxdiff[plane]);
    float nP = fminf((float)maxraw[plane * 32 + b], 100.0f);
    float nG = fminf((float)maxraw[plane * 32 + 16 + b], 100.0f);
    float acc = 0.0f;
    #pragma unroll
    for (int k = 0; k < 4; ++k) {
        uint4 wp = *(const uint4*)&P[(k << 10) + (threadIdx.x << 2)];
        uint4 wg = *(const uint4*)&G[(k << 10) + (threadIdx.x << 2)];
        #pragma unroll
        for (int w = 0; w < 4; ++w) {
            unsigned up = (&wp.x)[w], ug = (&wg.x)[w];
            #pragma unroll
            for (int s = 0; s < 32; s += 8) {
                float pn = fminf((float)((up >> s) & 255u), 100.0f) / nP;
                float gn = fminf((float)((ug >> s) & 255u), 100.0f) / nG;
                float d = fabsf(pn - gn);
                acc += (d <= c) ? d : (d * d + c * c) / (2.0f * c);
            }
        }
    }
    acc = blockSumF(acc);
    if (threadIdx.x == 0) atomicAdd(out, acc / 4194304.0f);
}

extern "C" void kernel_launch(void* const* d_in, const int* in_sizes, int n_in,
                              void* d_out, int out_size, void* d_ws, size_t ws_size,
                              hipStream_t stream) {
    const float* pred = (const float*)d_in[0];
    const float* gt   = (const float*)d_in[1];
    float* out        = (float*)d_out;
    char* ws          = (char*)d_ws;

    float* tbl        = (float*)ws;
    unsigned* maxz    = (unsigned*)(ws + MAXZ_OFF_B);
    unsigned* maxraw  = maxz;
    unsigned* maxdiff = maxz + 96;
    unsigned* hp      = (unsigned*)(ws + HIST_OFF_B);
    unsigned short* buck = (unsigned short*)(ws + BUCK_OFF_B);

    trig_kernel<<<6, 256, 0, stream>>>(tbl, maxz, out);
    bin_kernel<<<4096, 256, 0, stream>>>(pred, gt, tbl, buck);
    scan_kernel<<<1536, 512, 0, stream>>>(buck, hp, maxraw);
    maxdiff_kernel<<<768, 256, 0, stream>>>(hp, maxraw, maxdiff);
    loss_kernel<<<768, 256, 0, stream>>>(hp, maxraw, maxdiff, out);
}

// Round 6
// 206.567 us; speedup vs baseline: 1.2295x; 1.2295x over previous
//
#include <hip/hip_runtime.h>

#define PI_F 3.14159265358979323846f

// ws layout (bytes):
//   0        : trig table — f32 cosphi[1024], sinphi[1024], costh[512],
//              sinth[512] = 12288 B (written by trig_kernel, read by bin)
//   24576    : maxz — u32 maxraw[3*32] then maxdiff[3] (zeroed by trig blk 0)
//   32768    : packed hist u8: 3 planes × 32 hists × 262144 bins = 24 MB
//   25198592 : bucket regions: 4096 bin-blocks × 24640 B each
//              (64 B header: u16 off[25]; 24576 B data: 12288 u16 in-band ids
//               segmented by bucket = plane*8 + band64)  -> ws end ≈ 126.2 MB
// NOTE: this is the round-2 (best measured, 211 µs) configuration plus the
// independently-verified trig table. Round-5 post-mortem: 48-bucket split,
// stride-33 counters, run-length merge, and header prefetch ALL measured
// negative; reverted.
#define MAXZ_OFF_B   24576
#define HIST_OFF_B   32768
#define BUCK_OFF_B   25198592
#define REGION_U16   12320          // region stride in u16 units (24640 B)

// Correctly-rounded a/20000 via Markstein refinement (bit-exact RN).
__device__ inline float div20000(float a) {
    const float r = 1.0f / 20000.0f;
    float q0 = a * r;
    float e = fmaf(-20000.0f, q0, a);
    return fmaf(e, r, q0);
}

__device__ inline int bin1(float v) {
    float f = rintf(div20000(v + 10000.0f) * 512.0f);
    return (int)fminf(fmaxf(f, 0.0f), 511.0f);
}

// Pass 0: compute the 1024 phi + 512 theta sin/cos pairs ONCE. Identical FP
// expressions to the original -> bit-identical values (verified absmax 0 in
// rounds 3/5). Block 0 also zeroes maxz + out.
__global__ __launch_bounds__(256) void trig_kernel(
    float* __restrict__ tbl, unsigned* __restrict__ maxz,
    float* __restrict__ out) {
    const int t = threadIdx.x + blockIdx.x * 256;
    if (blockIdx.x == 0) {
        if (threadIdx.x < 128) maxz[threadIdx.x] = 0u;
        if (threadIdx.x == 128) out[0] = 0.0f;
    }
    if (t < 1024) {
        float fj = (float)t;
        float phi = PI_F * ((2.0f * fj) / 1023.0f - 1.0f);
        tbl[t] = cosf(phi);
        tbl[1024 + t] = sinf(phi);
    } else {
        int i = t - 1024;                       // < 512
        float fi = (float)i;
        float theta = -PI_F * (fi / 511.0f - 0.5f);
        tbl[2048 + i] = cosf(theta);
        tbl[2560 + i] = sinf(theta);
    }
}

// Pass 1: 4096 blocks = (xcd[0:2], i4[3:9], hh[10:11]), 4 rows/block,
// XCD-pinned (wg&7 == h&7). Bucket-sort of 4096 points × 3 planes into 24
// (plane, 64-row band) segments — round-2 version (best measured: 79.9 µs,
// conflicts 7.4M) with trig from table instead of in-kernel sincos.
//  * rank counters replicated 8× (cnt[(b<<3)|rep], rep=tid&7): max rank =
//    32 threads × 16 same-plane items = 512 -> rank 0..511 fits 9 bits:
//    item = [bucket:5][rep:3][rank:9][id:15].
//  * ids scattered into LDS staging (u16 scatter ~2-way = free) then copied
//    out as exactly 6 coalesced uint4 stores per thread.
// Ranks nondeterministic, counts exact -> downstream bit-identical.
__global__ __launch_bounds__(256) void bin_kernel(
    const float* __restrict__ pred, const float* __restrict__ gt,
    const float* __restrict__ tbl, unsigned short* __restrict__ buck) {
    __shared__ unsigned cnt[192];               // 24 buckets × 8 replicas
    __shared__ unsigned bsum[24];
    __shared__ unsigned off[25];
    __shared__ __align__(16) unsigned short sdata[12288];
    const int tid = threadIdx.x, wg = blockIdx.x;
    const unsigned rep = (unsigned)(tid & 7);
    const int xcd = wg & 7, i4 = (wg >> 3) & 127, hh = wg >> 10;
    const int h = (hh << 3) | xcd;
    if (tid < 192) cnt[tid] = 0u;
    const float4 cp4 = *(const float4*)&tbl[tid << 2];          // cos phi
    const float4 sp4 = *(const float4*)&tbl[1024 + (tid << 2)]; // sin phi
    const float4 ct4 = *(const float4*)&tbl[2048 + (i4 << 2)];  // cos theta
    const float4 st4 = *(const float4*)&tbl[2560 + (i4 << 2)];  // sin theta
    __syncthreads();
    const float* img = ((h >> 4) ? gt : pred) + ((h & 15) << 19);
    // item = [bucket:5][rep:3][rank:9][id:15]
    unsigned items[48];
    #pragma unroll
    for (int r = 0; r < 4; ++r) {
        const int i = i4 * 4 + r;
        const float4 d4 = *(const float4*)(img + (i << 10) + (tid << 2));
        const float ct = (&ct4.x)[r], st = (&st4.x)[r];
        #pragma unroll
        for (int k = 0; k < 4; ++k) {
            float d = (&d4.x)[k];
            float aA = (&cp4.x)[k] * ct;        // identical op order to r3/r5
            float aB = (&sp4.x)[k] * ct;
            float A = (d * aA) * 1000.0f;
            float B = (d * aB) * 1000.0f;
            float C = (d * (-st)) * 1000.0f;
            int iA = bin1(A), iB = bin1(B), iC = bin1(C);
            // plane0: y=iB,x=iA; plane1: y=iC,x=iA; plane2: y=iC,x=iB
            unsigned f0 = ((unsigned)iB << 9) | (unsigned)iA;   // 18-bit y*512+x
            unsigned f1 = ((unsigned)iC << 9) | (unsigned)iA;
            unsigned f2 = ((unsigned)iC << 9) | (unsigned)iB;
            unsigned b0 = f0 >> 15;                             // band64 of y
            unsigned b1 = 8u + (f1 >> 15);
            unsigned b2 = 16u + (f2 >> 15);
            unsigned r0 = atomicAdd(&cnt[(b0 << 3) | rep], 1u);
            unsigned r1 = atomicAdd(&cnt[(b1 << 3) | rep], 1u);
            unsigned r2 = atomicAdd(&cnt[(b2 << 3) | rep], 1u);
            const int base = (r * 4 + k) * 3;
            items[base + 0] = (b0 << 27) | (rep << 24) | (r0 << 15) | (f0 & 32767u);
            items[base + 1] = (b1 << 27) | (rep << 24) | (r1 << 15) | (f1 & 32767u);
            items[base + 2] = (b2 << 27) | (rep << 24) | (r2 << 15) | (f2 & 32767u);
        }
    }
    __syncthreads();
    // 3-level prefix: intra-bucket over 8 replicas, across 24 buckets,
    // then convert cnt[] to absolute sub-segment bases.
    if (tid < 24) {
        unsigned s = 0;
        #pragma unroll
        for (int r = 0; r < 8; ++r) {
            unsigned t = cnt[(tid << 3) | r];
            cnt[(tid << 3) | r] = s;
            s += t;
        }
        bsum[tid] = s;
    }
    __syncthreads();
    if (tid == 0) {
        unsigned s = 0;
        #pragma unroll
        for (int b = 0; b < 24; ++b) { off[b] = s; s += bsum[b]; }
        off[24] = s;                            // == 12288
    }
    __syncthreads();
    if (tid < 24) {
        unsigned o = off[tid];
        #pragma unroll
        for (int r = 0; r < 8; ++r) cnt[(tid << 3) | r] += o;
    }
    __syncthreads();
    // scatter into LDS staging (u16 scatter in LDS, ~2-way conflicts = free)
    #pragma unroll
    for (int t = 0; t < 48; ++t) {
        const unsigned it = items[t];
        const unsigned slot = ((it >> 27) << 3) | ((it >> 24) & 7u);
        sdata[cnt[slot] + ((it >> 15) & 511u)] = (unsigned short)(it & 32767u);
    }
    __syncthreads();
    unsigned short* regG = buck + (size_t)wg * REGION_U16;
    if (tid < 25) regG[tid] = (unsigned short)off[tid];
    // coalesced copy-out: 12288 u16 = 1536 uint4 = 6 per thread exactly
    const uint4* s4p = (const uint4*)sdata;
    uint4* g4 = (uint4*)(regG + 32);            // data after 64 B header
    #pragma unroll
    for (int c = 0; c < 6; ++c) g4[(c << 8) + tid] = s4p[(c << 8) + tid];
}

// Pass 2: WG = (plane, h, band); 1024 threads, 2 blocks/CU = 32 waves/CU.
// Each wave streams the (plane,band) segments of 8 of the 128 bin-block
// regions for this h as uint4 (8 ids/lane), plain 8 atomics per quad —
// round-2 version (best measured; run-merge and header-prefetch both
// measured negative on uniform-random data).
// blockIdx bits: [0:2]=xcd==h&7 (L2 pin), [3:4]=h>>3, [5:9]=X (LPT order).
__global__ __launch_bounds__(1024, 8) void scan_kernel(
    const unsigned short* __restrict__ buck, unsigned* __restrict__ hp,
    unsigned* __restrict__ maxraw) {
    __shared__ unsigned lh[16384];              // 64 rows × 512 bins, u16×2
    __shared__ unsigned s4[16];
    const int tid = threadIdx.x, wg = blockIdx.x;
    const int xcd = wg & 7, hhi = (wg >> 3) & 3;
    const int X = wg >> 5;                      // 0..23
    const int pair = X / 6, idx6 = X % 6;
    const int plane = idx6 >> 1;
    const int band = (idx6 & 1) ? (4 + pair) : (3 - pair);
    const int h = (hhi << 3) | xcd;
    const int bucket = plane * 8 + band;

    #pragma unroll
    for (int k = 0; k < 4; ++k)
        *(uint4*)&lh[(k << 12) + (tid << 2)] = make_uint4(0, 0, 0, 0);
    __syncthreads();

    const int wid = tid >> 6, lane = tid & 63;
    for (int i4 = wid; i4 < 128; i4 += 16) {
        const unsigned short* reg =
            buck + (size_t)(xcd | (i4 << 3) | (hhi << 10)) * REGION_U16;
        const int lo = reg[bucket], hi = reg[bucket + 1];
        const unsigned short* data = reg + 32;
        int a = (lo + 7) & ~7;                  // first 16B-aligned index
        if (a > hi) a = hi;
        const int head = a - lo;                // <= 7
        if (lane < head) {
            const unsigned id = data[lo + lane];
            atomicAdd(&lh[id >> 1], 1u << ((id & 1u) << 4));
        }
        const int nv = (hi - a) >> 3;           // full uint4 groups
        for (int v = lane; v < nv; v += 64) {
            const uint4 w = *(const uint4*)&data[a + (v << 3)];
            #pragma unroll
            for (int q = 0; q < 4; ++q) {
                const unsigned u = (&w.x)[q];
                const unsigned idl = u & 65535u, idh = u >> 16;
                atomicAdd(&lh[idl >> 1], 1u << ((idl & 1u) << 4));
                atomicAdd(&lh[idh >> 1], 1u << ((idh & 1u) << 4));
            }
        }
        const int tail = (hi - a) & 7;          // <= 7
        if (lane < tail) {
            const unsigned id = data[a + (nv << 3) + lane];
            atomicAdd(&lh[id >> 1], 1u << ((id & 1u) << 4));
        }
    }
    __syncthreads();

    // pack to u8 (sat 255; downstream clamps at 100) + raw band max
    unsigned m = 0;
    unsigned* gout = hp + ((plane * 32 + h) << 16) + (band << 13);
    #pragma unroll
    for (int k = 0; k < 8; ++k) {
        int w = (k << 10) + tid;
        unsigned v0 = lh[2 * w], v1 = lh[2 * w + 1];
        unsigned c0 = v0 & 65535u, c1 = v0 >> 16;
        unsigned c2 = v1 & 65535u, c3 = v1 >> 16;
        m = max(max(m, max(c0, c1)), max(c2, c3));
        gout[w] = min(c0, 255u) | (min(c1, 255u) << 8) |
                  (min(c2, 255u) << 16) | (min(c3, 255u) << 24);
    }
    #pragma unroll
    for (int o = 32; o; o >>= 1) m = max(m, (unsigned)__shfl_down((int)m, o));
    if ((tid & 63) == 0) s4[tid >> 6] = m;
    __syncthreads();
    if (tid == 0) {
        #pragma unroll
        for (int k = 1; k < 16; ++k) m = max(m, s4[k]);
        atomicMax(&maxraw[plane * 32 + h], m);
    }
}

__device__ inline float blockMaxF(float v) {
    #pragma unroll
    for (int o = 32; o; o >>= 1) v = fmaxf(v, __shfl_down(v, o));
    __shared__ float s[4];
    if ((threadIdx.x & 63) == 0) s[threadIdx.x >> 6] = v;
    __syncthreads();
    if (threadIdx.x == 0) v = fmaxf(fmaxf(s[0], s[1]), fmaxf(s[2], s[3]));
    return v;
}

__device__ inline float blockSumF(float v) {
    #pragma unroll
    for (int o = 32; o; o >>= 1) v += __shfl_down(v, o);
    __shared__ float s[4];
    if ((threadIdx.x & 63) == 0) s[threadIdx.x >> 6] = v;
    __syncthreads();
    if (threadIdx.x == 0) v = (s[0] + s[1]) + (s[2] + s[3]);
    return v;
}

// 768 blocks = 3 planes × 16 b × 16 chunks; uint4 loads, 16 bins/word-quad.
__global__ void maxdiff_kernel(const unsigned* __restrict__ hp,
                               const unsigned* __restrict__ maxraw,
                               unsigned* __restrict__ maxdiff) {
    int blk = blockIdx.x;
    int b = blk & 15, chunk = (blk >> 4) & 15, plane = blk >> 8;
    const unsigned* P = hp + ((plane * 32 + b) << 16) + (chunk << 12);
    const unsigned* G = P + (16 << 16);
    float nP = fminf((float)maxraw[plane * 32 + b], 100.0f);
    float nG = fminf((float)maxraw[plane * 32 + 16 + b], 100.0f);
    float m = 0.0f;
    #pragma unroll
    for (int k = 0; k < 4; ++k) {
        uint4 wp = *(const uint4*)&P[(k << 10) + (threadIdx.x << 2)];
        uint4 wg = *(const uint4*)&G[(k << 10) + (threadIdx.x << 2)];
        #pragma unroll
        for (int w = 0; w < 4; ++w) {
            unsigned up = (&wp.x)[w], ug = (&wg.x)[w];
            #pragma unroll
            for (int s = 0; s < 32; s += 8) {
                float pn = fminf((float)((up >> s) & 255u), 100.0f) / nP;
                float gn = fminf((float)((ug >> s) & 255u), 100.0f) / nG;
                m = fmaxf(m, fabsf(pn - gn));
            }
        }
    }
    m = blockMaxF(m);
    if (threadIdx.x == 0) atomicMax(&maxdiff[plane], __float_as_uint(m));
}

// Accumulates directly into out[0] (pre-zeroed by trig block 0):
// blocksum/2^22 is an exact power-of-2 scale, then one atomicAdd per block.
__global__ void loss_kernel(const unsigned* __restrict__ hp,
                            const unsigned* __restrict__ maxraw,
                            const unsigned* __restrict__ maxdiff,
                            float* __restrict__ out) {
    int blk = blockIdx.x;
    int b = blk & 15, chunk = (blk >> 4) & 15, plane = blk >> 8;
    const unsigned* P = hp + ((plane * 32 + b) << 16) + (chunk << 12);
    const unsigned* G = P + (16 << 16);
    float c = 0.2f * __uint_as_float(maxdiff[plane]);
    float nP = fminf((float)maxraw[plane * 32 + b], 100.0f);
    float nG = fminf((float)maxraw[plane * 32 + 16 + b], 100.0f);
    float acc = 0.0f;
    #pragma unroll
    for (int k = 0; k < 4; ++k) {
        uint4 wp = *(const uint4*)&P[(k << 10) + (threadIdx.x << 2)];
        uint4 wg = *(const uint4*)&G[(k << 10) + (threadIdx.x << 2)];
        #pragma unroll
        for (int w = 0; w < 4; ++w) {
            unsigned up = (&wp.x)[w], ug = (&wg.x)[w];
            #pragma unroll
            for (int s = 0; s < 32; s += 8) {
                float pn = fminf((float)((up >> s) & 255u), 100.0f) / nP;
                float gn = fminf((float)((ug >> s) & 255u), 100.0f) / nG;
                float d = fabsf(pn - gn);
                acc += (d <= c) ? d : (d * d + c * c) / (2.0f * c);
            }
        }
    }
    acc = blockSumF(acc);
    if (threadIdx.x == 0) atomicAdd(out, acc / 4194304.0f);
}

extern "C" void kernel_launch(void* const* d_in, const int* in_sizes, int n_in,
                              void* d_out, int out_size, void* d_ws, size_t ws_size,
                              hipStream_t stream) {
    const float* pred = (const float*)d_in[0];
    const float* gt   = (const float*)d_in[1];
    float* out        = (float*)d_out;
    char* ws          = (char*)d_ws;

    float* tbl        = (float*)ws;
    unsigned* maxz    = (unsigned*)(ws + MAXZ_OFF_B);
    unsigned* maxraw  = maxz;
    unsigned* maxdiff = maxz + 96;
    unsigned* hp      = (unsigned*)(ws + HIST_OFF_B);
    unsigned short* buck = (unsigned short*)(ws + BUCK_OFF_B);

    trig_kernel<<<6, 256, 0, stream>>>(tbl, maxz, out);
    bin_kernel<<<4096, 256, 0, stream>>>(pred, gt, tbl, buck);
    scan_kernel<<<768, 1024, 0, stream>>>(buck, hp, maxraw);
    maxdiff_kernel<<<768, 256, 0, stream>>>(hp, maxraw, maxdiff);
    loss_kernel<<<768, 256, 0, stream>>>(hp, maxraw, maxdiff, out);
}